// Round 8
// baseline (171.668 us; speedup 1.0000x reference)
//
#include <hip/hip_runtime.h>

// VQ-VAE vector quantizer, MI355X gfx950 — round 12: barrier-free score.
//  r5-r11: six structures, all ~60-90 µs, all pipes <25% busy; r11 reached
//  16 waves/CU and still 60 µs => the 2-barrier+waitcnt-per-tile loop
//  skeleton is the floor (per-iter 4500 cyc vs ~2800 cyc of pipe work).
//  Fix: remove the skeleton. vq_score reads B DIRECTLY from L2-resident
//  wbf into registers: block = 32 rows x 4 code-quarter waves, af[2][8]
//  (64 VGPR), score-only LDS 39 KB -> 4 blk/CU, grid 1024, ZERO barriers /
//  vmcnt / DMA in the main loop. In-block 4-way argmin merge; loss
//  (sum||z||^2 + sum best) finalized in score. vq_gather: proven rotated
//  DMA-gather + transposed z_q write, reading final indices.

#define DIM      256
#define NCODES   1024
#define SPB      1024
#define ZQ_ELEMS 8388608
#define NROWS    32768
#define NBLK_A   1024      // 32768 rows / 32
#define NBLK_B   512       // 32768 rows / 64

typedef float f32x4  __attribute__((ext_vector_type(4)));
typedef float f32x2  __attribute__((ext_vector_type(2)));
typedef short bf16x8 __attribute__((ext_vector_type(8)));
typedef short bf16x4 __attribute__((ext_vector_type(4)));
typedef short bf16x2 __attribute__((ext_vector_type(2)));

__device__ __forceinline__ short f2bf(float f) {
    union { float f; unsigned u; } v; v.f = f;
    unsigned r = v.u + 0x7FFFu + ((v.u >> 16) & 1u);   // RNE
    return (short)(r >> 16);
}

#define GLL16(g, l)                                                            \
    __builtin_amdgcn_global_load_lds(                                          \
        (const __attribute__((address_space(1))) void*)(g),                    \
        (__attribute__((address_space(3))) void*)(l), 16, 0, 0)

#define WAITV0 asm volatile("s_waitcnt vmcnt(0)" ::: "memory")

// ---------------- K1: prep ----------------
__global__ __launch_bounds__(256) void prep(const float* __restrict__ w,
                                            short* __restrict__ wbf,
                                            float* __restrict__ wn,
                                            float* __restrict__ acc,
                                            unsigned* __restrict__ done) {
    const int t = threadIdx.x, wv = t >> 6, l = t & 63;
    const int k = blockIdx.x * 4 + wv;          // one wave per code
    const float* wr = w + (size_t)k * DIM + 4 * l;
    f32x4 v = *(const f32x4*)wr;
    bf16x4 p;
    p[0] = f2bf(v[0]); p[1] = f2bf(v[1]); p[2] = f2bf(v[2]); p[3] = f2bf(v[3]);
    *(bf16x4*)(wbf + (size_t)k * DIM + 4 * l) = p;
    float s = v[0]*v[0] + v[1]*v[1] + v[2]*v[2] + v[3]*v[3];
#pragma unroll
    for (int off = 32; off; off >>= 1) s += __shfl_down(s, off);
    if (l == 0) wn[k] = s;
    if (blockIdx.x == 0 && t == 0) { *acc = 0.f; *done = 0u; }
}

// ---------------- K2a: score (32 rows x all 1024 codes per block) ----------
// LDS: zs bf16 [256 d][66 s-stride] (33792 B) + wnl f32[1024] (4 KB)
//      + barrv/barri + zsq  -> ~39 KB -> 4 blocks/CU.
// One __syncthreads after staging, one before the merge. Main loop has no
// barriers, no waitcnt, no LDS traffic for B.
__global__ __launch_bounds__(256)
__attribute__((amdgpu_waves_per_eu(3, 4)))
void vq_score(const float* __restrict__ z,
              const short* __restrict__ wbf,
              const float* __restrict__ wn,
              int* __restrict__ idxg,
              float* __restrict__ acc) {
    __shared__ __align__(16) short zs[256 * 66];   // [256 d][stride 66] bf16
    __shared__ __align__(16) float wnl[NCODES];
    __shared__ float barrv[128];
    __shared__ int   barri[128];
    __shared__ float zsq[4];

    const int t   = threadIdx.x;   // 0..255
    const int wv  = t >> 6;        // 0..3  (code-quarter)
    const int l   = t & 63;
    const int n16 = l & 15;
    const int q   = l >> 4;

    const int n0    = blockIdx.x * 32;
    const int batch = n0 >> 10;
    const int sbase = n0 & 1023;
    const float* zb = z + (size_t)batch * DIM * SPB + sbase;

    // ---- phase 1: z -> LDS bf16 [d][s] + sum(z^2); wn -> LDS
    // thread (cg = t>>4, sx = t&15): s = 2sx..2sx+1, c = cg + 16*ci.
    // write bank = (c + sx) % 32 -> ~2-way, free. global read 8B x 16 lanes
    // = 128B contiguous per c-row segment.
    {
        const int sx = t & 15;
        const int cg = t >> 4;
        float lsq = 0.f;
#pragma unroll
        for (int ci = 0; ci < 16; ++ci) {
            const int c = cg + 16 * ci;
            f32x2 v = *(const f32x2*)(zb + (size_t)c * SPB + 2 * sx);
            bf16x2 p;
            p[0] = f2bf(v[0]); p[1] = f2bf(v[1]);
            *(bf16x2*)&zs[66 * c + 2 * sx] = p;
            lsq += v[0]*v[0] + v[1]*v[1];
        }
#pragma unroll
        for (int off = 32; off; off >>= 1) lsq += __shfl_down(lsq, off);
        if (l == 0) zsq[wv] = lsq;
    }
    *(f32x4*)&wnl[4 * t] = *(const f32x4*)(wn + 4 * t);
    __syncthreads();

    // ---- phase 2: A fragments for the block's 32 rows (2 groups of 16)
    // lane (q,n16): row = 16g+n16, dims d = 32T+8q+j (2-way banks, free)
    bf16x8 af[2][8];
#pragma unroll
    for (int g = 0; g < 2; ++g)
#pragma unroll
        for (int T = 0; T < 8; ++T) {
            bf16x8 a;
#pragma unroll
            for (int j = 0; j < 8; ++j)
                a[j] = zs[66 * (32 * T + 8 * q + j) + 16 * g + n16];
            af[g][T] = a;
        }

    // ---- phase 3: codes [256*wv, 256*wv+256), B direct from L2, no LDS,
    // no barriers. Per kt: 8 x 16B loads (64B-coalesced), 16 MFMA, 8 VALU.
    const int kw = wv << 8;
    const short* wrow = wbf + ((size_t)(kw + n16) << 8) + 8 * q;

    float best[2][4];
    int   bidx[2][4];
#pragma unroll
    for (int g = 0; g < 2; ++g)
#pragma unroll
        for (int r = 0; r < 4; ++r) { best[g][r] = 3.4e38f; bidx[g][r] = 0; }

#pragma unroll 2
    for (int kt = 0; kt < 16; ++kt) {
        const short* hp = wrow + kt * 4096;    // +16 codes
        bf16x8 b[8];
#pragma unroll
        for (int T = 0; T < 8; ++T) b[T] = *(const bf16x8*)(hp + 32 * T);
        const int   k  = kw + 16 * kt + n16;
        const float wk = wnl[k];
        f32x4 a0 = {0.f, 0.f, 0.f, 0.f};
        f32x4 a1 = {0.f, 0.f, 0.f, 0.f};
        __builtin_amdgcn_s_setprio(1);
#pragma unroll
        for (int T = 0; T < 8; ++T) {
            a0 = __builtin_amdgcn_mfma_f32_16x16x32_bf16(af[0][T], b[T], a0, 0, 0, 0);
            a1 = __builtin_amdgcn_mfma_f32_16x16x32_bf16(af[1][T], b[T], a1, 0, 0, 0);
        }
        __builtin_amdgcn_s_setprio(0);
#pragma unroll
        for (int r = 0; r < 4; ++r) {
            float d0 = wk - 2.f * a0[r];
            if (d0 < best[0][r]) { best[0][r] = d0; bidx[0][r] = k; }
            float d1 = wk - 2.f * a1[r];
            if (d1 < best[1][r]) { best[1][r] = d1; bidx[1][r] = k; }
        }
    }

    // ---- phase 4: argmin. 16-lane reduce, then 4-way quarter merge in LDS.
    // row (within block) = 16g + 4q + r.
#pragma unroll
    for (int g = 0; g < 2; ++g)
#pragma unroll
        for (int r = 0; r < 4; ++r) {
            float bv = best[g][r];
            int   bi = bidx[g][r];
#pragma unroll
            for (int m = 1; m < 16; m <<= 1) {
                float ov = __shfl_xor(bv, m);
                int   oi = __shfl_xor(bi, m);
                if (ov < bv || (ov == bv && oi < bi)) { bv = ov; bi = oi; }
            }
            if (n16 == 0) {
                const int row = 16 * g + 4 * q + r;
                barrv[32 * wv + row] = bv;
                barri[32 * wv + row] = bi;
            }
        }
    __syncthreads();

    if (t < 32) {                  // merge 4 quarters; write final indices
        float bv = barrv[t];
        int   bi = barri[t];
#pragma unroll
        for (int w2 = 1; w2 < 4; ++w2) {
            const float ov = barrv[32 * w2 + t];
            const int   oi = barri[32 * w2 + t];
            if (ov < bv || (ov == bv && oi < bi)) { bv = ov; bi = oi; }
        }
        idxg[n0 + t] = bi;
        float rs = bv;             // winning distance of this row
#pragma unroll
        for (int off = 16; off; off >>= 1) rs += __shfl_down(rs, off);
        if (t == 0)
            atomicAdd(acc, rs + zsq[0] + zsq[1] + zsq[2] + zsq[3]);
    }
}

// ---------------- K2b: gather + z_q write + loss finalize ----------------
// LDS: zql fp32 64 rows x 1 KB (65536 B, rotated) + sidx i32[64]
__global__ __launch_bounds__(256)
void vq_gather(const float* __restrict__ w,
               const int* __restrict__ idxg,
               float* __restrict__ out,
               float* __restrict__ acc,
               unsigned* __restrict__ done) {
    __shared__ __align__(16) char smem[65536];
    __shared__ int sidx[64];

    float* zql = (float*)smem;     // [64 s][256 dwords], s-rotated

    const int t  = threadIdx.x;
    const int wv = t >> 6;
    const int l  = t & 63;

    const int n0    = blockIdx.x * 64;
    const int batch = n0 >> 10;
    const int sbase = n0 & 1023;
    float* ob = out + (size_t)batch * DIM * SPB + sbase;

    if (t < 64) sidx[t] = idxg[n0 + t];
    __syncthreads();

    // ---- DMA-gather 64 selected rows (1 KB each), rotated by (j>>2) granules
    // logical dword c of row j lands at phys dword (c + 4*(j>>2)) & 255
#pragma unroll
    for (int i = 0; i < 16; ++i) {
        const int j  = 16 * wv + i;
        const int ks = sidx[j];
        const float* src = w + ((size_t)ks << 8) + 4 * ((l - (j >> 2)) & 63);
        GLL16(src, (char*)smem + j * 1024 + l * 16);
    }
    WAITV0;
    __syncthreads();

    // ---- transposed z_q write (bank = cg+4u mod 32: exactly 2-way, free)
    {
        const int u  = t & 7;      // s-quad within 32-row window
        const int cg = t >> 3;     // 32 channel groups
#pragma unroll
        for (int p = 0; p < 2; ++p) {
#pragma unroll
            for (int ci = 0; ci < 8; ++ci) {
                const int c = cg + 32 * ci;
                f32x4 qv;
#pragma unroll
                for (int r = 0; r < 4; ++r)
                    qv[r] = zql[(32 * p + 4 * u + r) * 256 +
                                ((c + 32 * p + 4 * u) & 255)];
                __builtin_nontemporal_store(
                    qv, (f32x4*)(ob + (size_t)c * SPB + 32 * p + 4 * u));
            }
        }
    }

    if (t == 0) {
        __threadfence();
        unsigned prev = atomicAdd(done, 1u);
        if (prev == NBLK_B - 1) {
            float val = atomicAdd(acc, 0.f) * (1.f / 8388608.f);
            out[ZQ_ELEMS]     = val;
            out[ZQ_ELEMS + 1] = val;
        }
    }
}

extern "C" void kernel_launch(void* const* d_in, const int* in_sizes, int n_in,
                              void* d_out, int out_size, void* d_ws, size_t ws_size,
                              hipStream_t stream) {
    const float* z = (const float*)d_in[0];
    const float* w = (const float*)d_in[1];
    float* out = (float*)d_out;

    char* ws = (char*)d_ws;
    short*    wbf  = (short*)ws;                   // 512 KB
    float*    wn   = (float*)(ws + 524288);        // 4 KB
    float*    acc  = (float*)(ws + 528384);
    unsigned* done = (unsigned*)(ws + 528388);
    int*      idxg = (int*)  (ws + 532480);        // 128 KB

    prep<<<256, 256, 0, stream>>>(w, wbf, wn, acc, done);
    vq_score<<<NBLK_A, 256, 0, stream>>>(z, wbf, wn, idxg, acc);
    vq_gather<<<NBLK_B, 256, 0, stream>>>(w, idxg, out, acc, done);
}

// Round 9
// 156.369 us; speedup vs baseline: 1.0978x; 1.0978x over previous
//
#include <hip/hip_runtime.h>

// VQ-VAE vector quantizer, MI355X gfx950 — round 13: conservation-law kernel.
//  B-fragment flux into registers = (32768/rows_per_wave) x 512 KB. All
//  16-rows/wave variants (r5,r9,r11,r12) move 1 GB and land ~60-75 µs with
//  every pipe <25% busy; the LDS pipe runs ~50% duty, rest lost to barrier
//  lockstep. Fix both: wave = ALL 64 rows (af[4][8]=128 VGPR) x private
//  quarter-codebook -> flux 256 MB, each staged byte LDS-read ONCE; private
//  depth-2 GLL ring per wave -> ZERO main-loop barriers (counted vmcnt(8) +
//  lgkmcnt(0) before the WAR overwrite). A-frags direct from L3-warm z (no
//  zs staging); exact fp32 sum(z^2) off the same loads. setprio removed.
//  waves_per_eu(2,2) pins the 256-VGPR budget (r6 spill lesson).
//  Distances/argmin bit-identical to r5 -> absmax unchanged.

#define DIM      256
#define NCODES   1024
#define SPB      1024
#define ZQ_ELEMS 8388608
#define NBLK     512       // 32768 rows / 64

typedef float f32x4  __attribute__((ext_vector_type(4)));
typedef short bf16x8 __attribute__((ext_vector_type(8)));
typedef short bf16x4 __attribute__((ext_vector_type(4)));

__device__ __forceinline__ short f2bf(float f) {
    union { float f; unsigned u; } v; v.f = f;
    unsigned r = v.u + 0x7FFFu + ((v.u >> 16) & 1u);   // RNE
    return (short)(r >> 16);
}

#define GLL16(g, l)                                                            \
    __builtin_amdgcn_global_load_lds(                                          \
        (const __attribute__((address_space(1))) void*)(g),                    \
        (__attribute__((address_space(3))) void*)(l), 16, 0, 0)

#define WAITV(n)  asm volatile("s_waitcnt vmcnt(" #n ")" ::: "memory")
#define WAITLGKM0 asm volatile("s_waitcnt lgkmcnt(0)" ::: "memory")
#define SCHED0    __builtin_amdgcn_sched_barrier(0)

// ---------------- K1: prep ----------------
__global__ __launch_bounds__(256) void prep(const float* __restrict__ w,
                                            short* __restrict__ wbf,
                                            float* __restrict__ wn,
                                            float* __restrict__ acc,
                                            unsigned* __restrict__ done) {
    const int t = threadIdx.x, wv = t >> 6, l = t & 63;
    const int k = blockIdx.x * 4 + wv;          // one wave per code
    const float* wr = w + (size_t)k * DIM + 4 * l;
    f32x4 v = *(const f32x4*)wr;
    bf16x4 p;
    p[0] = f2bf(v[0]); p[1] = f2bf(v[1]); p[2] = f2bf(v[2]); p[3] = f2bf(v[3]);
    *(bf16x4*)(wbf + (size_t)k * DIM + 4 * l) = p;
    float s = v[0]*v[0] + v[1]*v[1] + v[2]*v[2] + v[3]*v[3];
#pragma unroll
    for (int off = 32; off; off >>= 1) s += __shfl_down(s, off);
    if (l == 0) wn[k] = s;
    if (blockIdx.x == 0 && t == 0) { *acc = 0.f; *done = 0u; }
}

// ---------------- K2: fused score+argmin+gather+loss ----------------
// LDS: smem 65536 B: main loop = 4 per-wave rings (2 x 8 KB each);
//      gather phase = zql 64 rows x 1 KB (wave wv's rows overlay its ring).
// + wnl f32[1024], barrv f32[256], barri i32[256], sidx i32[64], zsq f32[1]
__global__ __launch_bounds__(256)
__attribute__((amdgpu_waves_per_eu(2, 2)))
void vq_fused(const float* __restrict__ z,
              const short* __restrict__ wbf,
              const float* __restrict__ wn,
              const float* __restrict__ w,
              float* __restrict__ out,
              float* __restrict__ acc,
              unsigned* __restrict__ done) {
    __shared__ __align__(16) char smem[65536];
    __shared__ __align__(16) float wnl[NCODES];
    __shared__ float barrv[256];
    __shared__ int   barri[256];
    __shared__ int   sidx[64];
    __shared__ float zsq[1];

    float* zql = (float*)smem;     // gather phase: [64 s][256 dwords], rotated

    const int t   = threadIdx.x;   // 0..255
    const int wv  = t >> 6;        // 0..3 (code-quarter owner)
    const int l   = t & 63;
    const int n16 = l & 15;
    const int q   = l >> 4;

    const int n0    = blockIdx.x * 64;
    const int batch = n0 >> 10;
    const int sbase = n0 & 1023;
    const float* zb = z   + (size_t)batch * DIM * SPB + sbase;
    float*       ob = out + (size_t)batch * DIM * SPB + sbase;

    // ---- phase A: A-fragments for ALL 64 rows direct from global z
    // lane (q,n16), frag (g,T): row = 16g+n16, dims 32T+8q+j. Each wave
    // touches every (row,dim) exactly once -> wave 0's fp32 sum is exact z^2.
    float lsq = 0.f;
    bf16x8 af[4][8];
#pragma unroll
    for (int g = 0; g < 4; ++g)
#pragma unroll
        for (int T = 0; T < 8; ++T) {
            bf16x8 a;
#pragma unroll
            for (int j = 0; j < 8; ++j) {
                float x = zb[(size_t)(32 * T + 8 * q + j) * SPB + 16 * g + n16];
                a[j] = f2bf(x);
                lsq += x * x;
            }
            af[g][T] = a;
        }
#pragma unroll
    for (int off = 32; off; off >>= 1) lsq += __shfl_down(lsq, off);
    if (wv == 0 && l == 0) zsq[0] = lsq;
    *(f32x4*)&wnl[4 * t] = *(const f32x4*)(wn + 4 * t);
    __syncthreads();               // wnl + zsq visible

    // ---- main loop: private depth-2 ring, 16 tiles x 16 codes, no barriers
    char* ring = smem + wv * 16384;                  // 2 x 8192 B
    const short* wq = wbf + ((size_t)wv << 16);      // 256*wv * DIM shorts

    // prologue: stage tiles 0,1 (8 GLL16 each; granule-XOR swizzled source)
#pragma unroll
    for (int pt = 0; pt < 2; ++pt) {
#pragma unroll
        for (int i = 0; i < 8; ++i) {
            const int nn = 2 * i + (l >> 5);         // code-in-tile 0..15
            const int pp = l & 31;                   // phys granule
            GLL16(wq + (size_t)pt * 4096 + nn * 256 + 8 * (pp ^ (nn & 7)),
                  ring + pt * 8192 + (64 * i + l) * 16);
        }
    }

    float best[4][4];
    int   bidx[4][4];
#pragma unroll
    for (int g = 0; g < 4; ++g)
#pragma unroll
        for (int r = 0; r < 4; ++r) { best[g][r] = 3.4e38f; bidx[g][r] = 0; }

    for (int kt = 0; kt < 16; ++kt) {
        if (kt < 15) { WAITV(8); }   // tile kt landed; kt+1 in flight
        else         { WAITV(0); }
        const char* bp = ring + (kt & 1) * 8192;
        bf16x8 b[8];
#pragma unroll
        for (int T = 0; T < 8; ++T)
            b[T] = *(const bf16x8*)(bp + n16 * 512 +
                                    (((4 * T + q) ^ (n16 & 7)) << 4));
        const int   k  = (wv << 8) + 16 * kt + n16;
        const float wk = wnl[k];
        WAITLGKM0;                   // b,wk in regs: safe to overwrite buf
        SCHED0;
        if (kt < 14) {               // stage tile kt+2 into buf (kt&1)
#pragma unroll
            for (int i = 0; i < 8; ++i) {
                const int nn = 2 * i + (l >> 5);
                const int pp = l & 31;
                GLL16(wq + (size_t)(kt + 2) * 4096 + nn * 256 + 8 * (pp ^ (nn & 7)),
                      ring + (kt & 1) * 8192 + (64 * i + l) * 16);
            }
        }
        f32x4 a0 = {0.f,0.f,0.f,0.f}, a1 = {0.f,0.f,0.f,0.f};
        f32x4 a2 = {0.f,0.f,0.f,0.f}, a3 = {0.f,0.f,0.f,0.f};
#pragma unroll
        for (int T = 0; T < 8; ++T) {
            a0 = __builtin_amdgcn_mfma_f32_16x16x32_bf16(af[0][T], b[T], a0, 0, 0, 0);
            a1 = __builtin_amdgcn_mfma_f32_16x16x32_bf16(af[1][T], b[T], a1, 0, 0, 0);
            a2 = __builtin_amdgcn_mfma_f32_16x16x32_bf16(af[2][T], b[T], a2, 0, 0, 0);
            a3 = __builtin_amdgcn_mfma_f32_16x16x32_bf16(af[3][T], b[T], a3, 0, 0, 0);
        }
#pragma unroll
        for (int r = 0; r < 4; ++r) {
            float d0 = wk - 2.f * a0[r];
            if (d0 < best[0][r]) { best[0][r] = d0; bidx[0][r] = k; }
            float d1 = wk - 2.f * a1[r];
            if (d1 < best[1][r]) { best[1][r] = d1; bidx[1][r] = k; }
            float d2 = wk - 2.f * a2[r];
            if (d2 < best[2][r]) { best[2][r] = d2; bidx[2][r] = k; }
            float d3 = wk - 2.f * a3[r];
            if (d3 < best[3][r]) { best[3][r] = d3; bidx[3][r] = k; }
        }
    }

    // ---- argmin: 16-lane reduce then 4-way cross-wave merge (r6-proven)
    // row (within block) = 16g + 4q + r
#pragma unroll
    for (int g = 0; g < 4; ++g)
#pragma unroll
        for (int r = 0; r < 4; ++r) {
            float bv = best[g][r];
            int   bi = bidx[g][r];
#pragma unroll
            for (int m = 1; m < 16; m <<= 1) {
                float ov = __shfl_xor(bv, m);
                int   oi = __shfl_xor(bi, m);
                if (ov < bv || (ov == bv && oi < bi)) { bv = ov; bi = oi; }
            }
            if (n16 == 0) {
                const int row = 16 * g + 4 * q + r;
                barrv[64 * wv + row] = bv;
                barri[64 * wv + row] = bi;
            }
        }
    __syncthreads();

    float blktot = 0.f;
    if (t < 64) {                  // wave 0: merge across 4 code-quarters
        float bv = barrv[t];
        int   bi = barri[t];
#pragma unroll
        for (int w2 = 1; w2 < 4; ++w2) {
            const float ov = barrv[64 * w2 + t];
            const int   oi = barri[64 * w2 + t];
            if (ov < bv || (ov == bv && oi < bi)) { bv = ov; bi = oi; }
        }
        sidx[t] = bi;
        float rs = bv;             // winning distance of this row
#pragma unroll
        for (int off = 32; off; off >>= 1) rs += __shfl_down(rs, off);
        if (t == 0) blktot = rs + zsq[0];
    }
    __syncthreads();               // sidx ready; rings dead

    // ---- gather: DMA 64 selected rows (1 KB each), rotated by (j>>2)
    // granules; wave wv writes rows 16wv..16wv+15 = its own former ring.
#pragma unroll
    for (int i = 0; i < 16; ++i) {
        const int j  = 16 * wv + i;
        const int ks = sidx[j];
        const float* src = w + ((size_t)ks << 8) + 4 * ((l - (j >> 2)) & 63);
        GLL16(src, (char*)smem + j * 1024 + l * 16);
    }
    WAITV(0);
    __syncthreads();

    // ---- transposed z_q write; phys dword (c + 4*(j>>2)) & 255, 2-way free
    {
        const int u  = t & 7;      // s-quad within 32-row window
        const int cg = t >> 3;     // 32 channel groups
#pragma unroll
        for (int p = 0; p < 2; ++p) {
#pragma unroll
            for (int ci = 0; ci < 8; ++ci) {
                const int c = cg + 32 * ci;
                f32x4 qv;
#pragma unroll
                for (int r = 0; r < 4; ++r)
                    qv[r] = zql[(32 * p + 4 * u + r) * 256 +
                                ((c + 32 * p + 4 * u) & 255)];
                __builtin_nontemporal_store(
                    qv, (f32x4*)(ob + (size_t)c * SPB + 32 * p + 4 * u));
            }
        }
    }

    if (t == 0) {
        atomicAdd(acc, blktot);
        __threadfence();
        unsigned prev = atomicAdd(done, 1u);
        if (prev == NBLK - 1) {
            float val = atomicAdd(acc, 0.f) * (1.f / 8388608.f);
            out[ZQ_ELEMS]     = val;
            out[ZQ_ELEMS + 1] = val;
        }
    }
}

extern "C" void kernel_launch(void* const* d_in, const int* in_sizes, int n_in,
                              void* d_out, int out_size, void* d_ws, size_t ws_size,
                              hipStream_t stream) {
    const float* z = (const float*)d_in[0];
    const float* w = (const float*)d_in[1];
    float* out = (float*)d_out;

    char* ws = (char*)d_ws;
    short*    wbf  = (short*)ws;                   // 512 KB
    float*    wn   = (float*)(ws + 524288);        // 4 KB
    float*    acc  = (float*)(ws + 528384);
    unsigned* done = (unsigned*)(ws + 528388);

    prep<<<256, 256, 0, stream>>>(w, wbf, wn, acc, done);
    vq_fused<<<NBLK, 256, 0, stream>>>(z, wbf, wn, w, out, acc, done);
}